// Round 23
// baseline (93.488 us; speedup 1.0000x reference)
//
#include <hip/hip_runtime.h>
#include <stdint.h>

// Binarized dense via i8 MFMA: C[r][u] = dot(sign(x[r,:]), sign(W[:,u])) + b[u]
// sign in {+1,-1} as i8 0x01/0xFF; i32 accumulation exact (|dot| <= 4096).
// v_mfma_i32_32x32x32_i8: A/B = v4i (16 i8), lane&31 = row/col, lane>>5 =
// k-16-half; C/D: col = lane&31, row = (r&3)+8*(r>>2)+4*(lane>>5).
// Layouts/maps HW-verified (rounds 12-22, absmax 0).
//
// v19 = v18 (r22, 89.35us) with the B-path decoupled from the x vmcnt queue:
// vmcnt is ONE ORDERED counter -> r22's on-demand B waits drained every older
// x load each step, serializing x's ~1600cy HBM stream with compute (measured
// step = serialized pipe sum). Now B flows via global_load_lds (T3/T4):
//  - wave wv stages ITS OWN 4KB B-slice for step s+1 into Bl[(s+1)&1]
//    (4x glds16; per-wave self-contained -> no barrier interaction),
//  - s_waitcnt vmcnt(6): B(s) complete, the 6 younger ops (4 B-stage(s+1)
//    + 2 x-loads of this gap) REMAIN IN FLIGHT,
//  - sched_barrier(0) (rule #18), then conflict-free lane-major ds_read_b128.
// Per-gap vm-op count is uniform (one XLD2 = 2) -> vmcnt(6) exact.
// LDS: Af 64KB + Bl 2x32KB = 128KB, 1 block/CU. x read from HBM once.
// Everything else identical to r22.

#define BATCH  16384
#define UNITS  512
#define KDIM   4096
#define KSTEP  64
#define NSTEP  (KDIM / KSTEP)   // 64
#define NPER8  (NSTEP / 8)      // 8 oct-periods
#define MROWS  64               // rows per block

typedef int v4i  __attribute__((ext_vector_type(4)));
typedef int v16i __attribute__((ext_vector_type(16)));

// split-protocol barrier: lgkm-drain only; vmcnt loads stay in flight
#define BARRIER()                                                              \
    do {                                                                       \
        asm volatile("s_waitcnt lgkmcnt(0)" ::: "memory");                     \
        __builtin_amdgcn_s_barrier();                                          \
        __builtin_amdgcn_sched_barrier(0);                                     \
    } while (0)

// async global->LDS, 16B per lane: lane i's 16B lands at ldsbase + i*16
__device__ __forceinline__ void glds16(const uint8_t* g, uint8_t* l) {
    __builtin_amdgcn_global_load_lds(
        (const __attribute__((address_space(1))) uint32_t*)g,
        (__attribute__((address_space(3))) uint32_t*)l, 16, 0, 0);
}

// ---- pack W: f32 [4096][512] -> Wb2 fragment-major i8 +/-1 (2 MB) ----------
// 16B chunk index ((s*16 + n5)*2 + ks)*64 + lane; lane = (n&31) + 32*k16half;
// covers col n5*32+(n&31), k = s*64 + ks*32 + k16half*16 + [0..15].
__global__ __launch_bounds__(256) void pack_w_kernel(const float* __restrict__ W,
                                                     uint8_t* __restrict__ Wb2) {
    int t  = blockIdx.x * 256 + threadIdx.x;   // 0..262143
    int n  = t & 511;                          // col
    int k0 = (t >> 9) * 8;                     // 8 consecutive k
    unsigned long long m = 0;
    #pragma unroll
    for (int j = 0; j < 8; ++j) {
        float v = W[(size_t)(k0 + j) * UNITS + n];
        m |= ((v < 0.f) ? 0xFFull : 0x01ull) << (8 * j);
    }
    int s  = k0 >> 6;
    int kk = k0 & 63;
    int ks = kk >> 5;
    int hi = (kk & 31) >> 4;
    int lane = (n & 31) + 32 * hi;
    size_t a = ((((size_t)s * 16 + (n >> 5)) * 2 + ks) * 64 + lane) * 16 + (kk & 15);
    *reinterpret_cast<unsigned long long*>(Wb2 + a) = m;
}

__device__ __forceinline__ uint32_t sgn4(float4 v) {
    uint32_t b0 = v.x < 0.f ? 0xFFu : 0x01u;
    uint32_t b1 = v.y < 0.f ? 0xFFu : 0x01u;
    uint32_t b2 = v.z < 0.f ? 0xFFu : 0x01u;
    uint32_t b3 = v.w < 0.f ? 0xFFu : 0x01u;
    return b0 | (b1 << 8) | (b2 << 16) | (b3 << 24);
}

// Af layout: byte = PB*32768 + sip*4096 + rt*2048 + ks*1024
//                 + ((row&31) + 32*k16half)*16 + off   (sip = 0..7)
// Bl layout: Bl[buf][wv*4096 + ct*2048 + ks*1024 + lane*16]

// one K-step: stage B(s+1) via glds, counted-vmcnt wait for B(s),
// read B from LDS + A-frags, 8 MFMA.
#define STEP(PB, SIP, Q)                                                       \
    {                                                                          \
        const int _sn = (8 * (Q) + (SIP) + 1 < NSTEP) ? 8 * (Q) + (SIP) + 1    \
                                                      : NSTEP - 1;             \
        const uint8_t* _gs = Wb2 + (size_t)_sn * 32768 + wv * 4096             \
                                 + (size_t)l * 16;                             \
        uint8_t* _ls = &Bl[_sn & 1][wv * 4096];                                \
        glds16(_gs,        _ls);                                               \
        glds16(_gs + 1024, _ls + 1024);                                        \
        glds16(_gs + 2048, _ls + 2048);                                        \
        glds16(_gs + 3072, _ls + 3072);                                        \
        asm volatile("s_waitcnt vmcnt(6)" ::: "memory");                       \
        __builtin_amdgcn_sched_barrier(0);                                     \
        const uint8_t* _bl = &Bl[(8 * (Q) + (SIP)) & 1][wv * 4096 + l * 16];   \
        v4i b0 = *reinterpret_cast<const v4i*>(_bl);           /* ct0 ks0 */   \
        v4i b1 = *reinterpret_cast<const v4i*>(_bl + 1024);    /* ct0 ks1 */   \
        v4i b2 = *reinterpret_cast<const v4i*>(_bl + 2048);    /* ct1 ks0 */   \
        v4i b3 = *reinterpret_cast<const v4i*>(_bl + 3072);    /* ct1 ks1 */   \
        const uint8_t* _a = &Af[(PB) * 32768 + (SIP) * 4096 + l * 16];         \
        v4i a00 = *reinterpret_cast<const v4i*>(_a);           /* rt0 ks0 */   \
        v4i a01 = *reinterpret_cast<const v4i*>(_a + 1024);    /* rt0 ks1 */   \
        v4i a10 = *reinterpret_cast<const v4i*>(_a + 2048);    /* rt1 ks0 */   \
        v4i a11 = *reinterpret_cast<const v4i*>(_a + 3072);    /* rt1 ks1 */   \
        __builtin_amdgcn_s_setprio(1);                                         \
        acc00 = __builtin_amdgcn_mfma_i32_32x32x32_i8(a00, b0, acc00, 0, 0, 0);\
        acc00 = __builtin_amdgcn_mfma_i32_32x32x32_i8(a01, b1, acc00, 0, 0, 0);\
        acc01 = __builtin_amdgcn_mfma_i32_32x32x32_i8(a00, b2, acc01, 0, 0, 0);\
        acc01 = __builtin_amdgcn_mfma_i32_32x32x32_i8(a01, b3, acc01, 0, 0, 0);\
        acc10 = __builtin_amdgcn_mfma_i32_32x32x32_i8(a10, b0, acc10, 0, 0, 0);\
        acc10 = __builtin_amdgcn_mfma_i32_32x32x32_i8(a11, b1, acc10, 0, 0, 0);\
        acc11 = __builtin_amdgcn_mfma_i32_32x32x32_i8(a10, b2, acc11, 0, 0, 0);\
        acc11 = __builtin_amdgcn_mfma_i32_32x32x32_i8(a11, b3, acc11, 0, 0, 0);\
        __builtin_amdgcn_s_setprio(0);                                         \
    }

// load this thread's 2 x-float4s (rows trow, trow+32) of absolute step S
#define XLD2(XA, XB, S)                                                        \
    {                                                                          \
        const int _sc = ((S) < NSTEP) ? (S) : NSTEP - 1;                       \
        XA = *reinterpret_cast<const float4*>(xr0 + (size_t)_sc * KSTEP);      \
        XB = *reinterpret_cast<const float4*>(xr0 + (size_t)32 * KDIM          \
                                                  + (size_t)_sc * KSTEP);      \
    }

// commit the pair into Af[PB], step-slot SIP (rt 0 and 1)
#define XCM2(PB, SIP, XA, XB)                                                  \
    {                                                                          \
        *reinterpret_cast<uint32_t*>(                                          \
            &Af[(PB) * 32768 + (SIP) * 4096 + awk]) = sgn4(XA);                \
        *reinterpret_cast<uint32_t*>(                                          \
            &Af[(PB) * 32768 + (SIP) * 4096 + 2048 + awk]) = sgn4(XB);         \
    }

// one oct-period: steps 8Q..8Q+7 read Af[PB]; commits A(8Q+8..+15) -> Af[PB^1]
// steady state: entering PERIOD(Q), (xA0,xA1) holds step 8Q+8 data.
// Every inter-STEP gap has exactly one XLD2 (2 vm ops) -> vmcnt(6) exact.
#define PERIOD(Q, PB)                                                          \
    {                                                                          \
        STEP(PB, 0, Q);                                                        \
        XLD2(xB0, xB1, 8 * (Q) + 9);                                           \
        STEP(PB, 1, Q);                                                        \
        XCM2((PB) ^ 1, 0, xA0, xA1);                                           \
        XLD2(xA0, xA1, 8 * (Q) + 10);                                          \
        STEP(PB, 2, Q);                                                        \
        XCM2((PB) ^ 1, 1, xB0, xB1);                                           \
        XLD2(xB0, xB1, 8 * (Q) + 11);                                          \
        STEP(PB, 3, Q);                                                        \
        XCM2((PB) ^ 1, 2, xA0, xA1);                                           \
        XLD2(xA0, xA1, 8 * (Q) + 12);                                          \
        STEP(PB, 4, Q);                                                        \
        XCM2((PB) ^ 1, 3, xB0, xB1);                                           \
        XLD2(xB0, xB1, 8 * (Q) + 13);                                          \
        STEP(PB, 5, Q);                                                        \
        XCM2((PB) ^ 1, 4, xA0, xA1);                                           \
        XLD2(xA0, xA1, 8 * (Q) + 14);                                          \
        STEP(PB, 6, Q);                                                        \
        XCM2((PB) ^ 1, 5, xB0, xB1);                                           \
        XLD2(xB0, xB1, 8 * (Q) + 15);                                          \
        STEP(PB, 7, Q);                                                        \
        XCM2((PB) ^ 1, 6, xA0, xA1);                                           \
        XLD2(xA0, xA1, 8 * (Q) + 16);  /* = 8(Q+1)+8: next period's sip0 */    \
        XCM2((PB) ^ 1, 7, xB0, xB1);                                           \
        BARRIER();                                                             \
    }

// ------------------------------- MFMA GEMM ----------------------------------
__global__ __launch_bounds__(512, 1) void mm_kernel(const float* __restrict__ x,
                                                    const uint8_t* __restrict__ Wb2,
                                                    const float* __restrict__ bias,
                                                    float* __restrict__ C) {
    __shared__ __attribute__((aligned(16))) uint8_t Af[2 * 32768];  // 64 KB
    __shared__ __attribute__((aligned(16))) uint8_t Bl[2][32768];   // 64 KB
    const int t   = threadIdx.x;
    const int l   = t & 63;
    const int wv  = t >> 6;              // wave 0..7 -> cols wv*64..+63
    const int lr  = l & 31;
    const int hi  = l >> 5;
    const int row0 = blockIdx.x * MROWS;

    // x staging (verified): thread t owns rows trow & trow+32, f4 at tak
    const int trow = t >> 4;             // 0..31
    const int tak  = (t & 15) * 4;       // 0..60
    const int awk = (tak >> 5) * 1024
                  + (trow + 32 * ((tak >> 4) & 1)) * 16 + (tak & 15);
    const float* xr0 = x + (size_t)(row0 + trow) * KDIM + tak;

    v16i acc00, acc01, acc10, acc11;
    #pragma unroll
    for (int e = 0; e < 16; ++e) { acc00[e] = 0; acc01[e] = 0;
                                   acc10[e] = 0; acc11[e] = 0; }

    float4 xA0, xA1, xB0, xB1;

    // ---- prologue: stage B(0) via glds; stage A steps 0..7; preload xA ----
    {
        const uint8_t* gs = Wb2 + wv * 4096 + (size_t)l * 16;
        uint8_t* ls = &Bl[0][wv * 4096];
        glds16(gs,        ls);
        glds16(gs + 1024, ls + 1024);
        glds16(gs + 2048, ls + 2048);
        glds16(gs + 3072, ls + 3072);
        float4 xa, xb;
        XLD2(xa, xb, 0); XCM2(0, 0, xa, xb);
        XLD2(xa, xb, 1); XCM2(0, 1, xa, xb);
        XLD2(xa, xb, 2); XCM2(0, 2, xa, xb);
        XLD2(xa, xb, 3); XCM2(0, 3, xa, xb);
        XLD2(xa, xb, 4); XCM2(0, 4, xa, xb);
        XLD2(xa, xb, 5); XCM2(0, 5, xa, xb);
        XLD2(xa, xb, 6); XCM2(0, 6, xa, xb);
        XLD2(xa, xb, 7); XCM2(0, 7, xa, xb);
        XLD2(xA0, xA1, 8);
        BARRIER();
    }

    #pragma unroll 1
    for (int q = 0; q < NPER8; q += 2) {
        PERIOD(q,     0);
        PERIOD(q + 1, 1);
    }

    // ---- epilogue: C = acc + bias (verified C/D map) ----
    {
        const int col0 = wv * 64 + lr;          // ct = 0
        const int col1 = wv * 64 + 32 + lr;     // ct = 1
        const float bv0 = bias[col0], bv1 = bias[col1];
        #pragma unroll
        for (int r = 0; r < 16; ++r) {
            int crow = (r & 3) + 8 * (r >> 2) + 4 * hi;
            C[(size_t)(row0 + crow) * UNITS + col0]      = (float)acc00[r] + bv0;
            C[(size_t)(row0 + crow) * UNITS + col1]      = (float)acc01[r] + bv1;
            C[(size_t)(row0 + 32 + crow) * UNITS + col0] = (float)acc10[r] + bv0;
            C[(size_t)(row0 + 32 + crow) * UNITS + col1] = (float)acc11[r] + bv1;
        }
    }
}

extern "C" void kernel_launch(void* const* d_in, const int* in_sizes, int n_in,
                              void* d_out, int out_size, void* d_ws, size_t ws_size,
                              hipStream_t stream) {
    const float* x = (const float*)d_in[0];
    const float* W = (const float*)d_in[1];
    const float* b = (const float*)d_in[2];
    float* out = (float*)d_out;

    uint8_t* Wb2 = (uint8_t*)d_ws;   // 2 MB fragment-major packed W

    pack_w_kernel<<<(512 * 512) / 256, 256, 0, stream>>>(W, Wb2);
    mm_kernel<<<BATCH / MROWS, 512, 0, stream>>>(x, Wb2, b, out);
}

// Round 24
// 90.929 us; speedup vs baseline: 1.0281x; 1.0281x over previous
//
#include <hip/hip_runtime.h>
#include <stdint.h>

// Binarized dense via i8 MFMA: C[r][u] = dot(sign(x[r,:]), sign(W[:,u])) + b[u]
// sign in {+1,-1} as i8 0x01/0xFF; i32 accumulation exact (|dot| <= 4096).
// v_mfma_i32_32x32x32_i8: A/B = v4i (16 i8), lane&31 = row/col, lane>>5 =
// k-16-half; C/D: col = lane&31, row = (r&3)+8*(r>>2)+4*(lane>>5).
// Layouts/maps HW-verified (rounds 12-23, absmax 0).
//
// FINAL (= r22, best measured 89.35us): oct-period schedule with
// non-draining barriers.
//  - block = 64 rows x 512 cols (512 thr, 8 waves), wave = 64x64 output
//    (2x2 32-tiles, acc 64 VGPR); grid 256 = 1 block/CU.
//  - x read from HBM exactly once; sgn4-packed to LDS A-frag dbuf
//    (Af 2x32KB, oct-period: 8 K-steps per barrier -> only 8 barriers).
//  - B on demand from L2 (fragment-major Wb2, 2MB resident; coalesced
//    1KB wave loads straight to registers; no B LDS).
//  - BARRIER() = lgkmcnt(0) + raw s_barrier + sched_barrier(0): vmcnt
//    loads deliberately stay in flight across barriers (T3/T4-lite).
//  - s_setprio(1) around MFMA clusters (T5).
// Search summary (r12-r23): occupancy/tile/B-path/barrier/issue-order
// variants all land 93-129us; this schedule is the measured optimum.

#define BATCH  16384
#define UNITS  512
#define KDIM   4096
#define KSTEP  64
#define NSTEP  (KDIM / KSTEP)   // 64
#define NPER8  (NSTEP / 8)      // 8 oct-periods
#define MROWS  64               // rows per block

typedef int v4i  __attribute__((ext_vector_type(4)));
typedef int v16i __attribute__((ext_vector_type(16)));

// split-protocol barrier: lgkm-drain only; vmcnt loads stay in flight
#define BARRIER()                                                              \
    do {                                                                       \
        asm volatile("s_waitcnt lgkmcnt(0)" ::: "memory");                     \
        __builtin_amdgcn_s_barrier();                                          \
        __builtin_amdgcn_sched_barrier(0);                                     \
    } while (0)

// ---- pack W: f32 [4096][512] -> Wb2 fragment-major i8 +/-1 (2 MB) ----------
// 16B chunk index ((s*16 + n5)*2 + ks)*64 + lane; lane = (n&31) + 32*k16half;
// covers col n5*32+(n&31), k = s*64 + ks*32 + k16half*16 + [0..15].
__global__ __launch_bounds__(256) void pack_w_kernel(const float* __restrict__ W,
                                                     uint8_t* __restrict__ Wb2) {
    int t  = blockIdx.x * 256 + threadIdx.x;   // 0..262143
    int n  = t & 511;                          // col
    int k0 = (t >> 9) * 8;                     // 8 consecutive k
    unsigned long long m = 0;
    #pragma unroll
    for (int j = 0; j < 8; ++j) {
        float v = W[(size_t)(k0 + j) * UNITS + n];
        m |= ((v < 0.f) ? 0xFFull : 0x01ull) << (8 * j);
    }
    int s  = k0 >> 6;
    int kk = k0 & 63;
    int ks = kk >> 5;
    int hi = (kk & 31) >> 4;
    int lane = (n & 31) + 32 * hi;
    size_t a = ((((size_t)s * 16 + (n >> 5)) * 2 + ks) * 64 + lane) * 16 + (kk & 15);
    *reinterpret_cast<unsigned long long*>(Wb2 + a) = m;
}

__device__ __forceinline__ uint32_t sgn4(float4 v) {
    uint32_t b0 = v.x < 0.f ? 0xFFu : 0x01u;
    uint32_t b1 = v.y < 0.f ? 0xFFu : 0x01u;
    uint32_t b2 = v.z < 0.f ? 0xFFu : 0x01u;
    uint32_t b3 = v.w < 0.f ? 0xFFu : 0x01u;
    return b0 | (b1 << 8) | (b2 << 16) | (b3 << 24);
}

// Af layout: byte = PB*32768 + sip*4096 + rt*2048 + ks*1024
//                 + ((row&31) + 32*k16half)*16 + off   (sip = 0..7)

// one K-step: 4 B-frags on demand (L2), 4 A-frags (2rt x 2ks), 8 MFMA
#define STEP(PB, SIP, Q)                                                       \
    {                                                                          \
        const uint8_t* _b = bbase + (size_t)(8 * (Q) + (SIP)) * 32768;         \
        v4i b0 = *reinterpret_cast<const v4i*>(_b);            /* ct0 ks0 */   \
        v4i b1 = *reinterpret_cast<const v4i*>(_b + 1024);     /* ct0 ks1 */   \
        v4i b2 = *reinterpret_cast<const v4i*>(_b + 2048);     /* ct1 ks0 */   \
        v4i b3 = *reinterpret_cast<const v4i*>(_b + 3072);     /* ct1 ks1 */   \
        const uint8_t* _a = &Af[(PB) * 32768 + (SIP) * 4096 + l * 16];         \
        v4i a00 = *reinterpret_cast<const v4i*>(_a);           /* rt0 ks0 */   \
        v4i a01 = *reinterpret_cast<const v4i*>(_a + 1024);    /* rt0 ks1 */   \
        v4i a10 = *reinterpret_cast<const v4i*>(_a + 2048);    /* rt1 ks0 */   \
        v4i a11 = *reinterpret_cast<const v4i*>(_a + 3072);    /* rt1 ks1 */   \
        __builtin_amdgcn_s_setprio(1);                                         \
        acc00 = __builtin_amdgcn_mfma_i32_32x32x32_i8(a00, b0, acc00, 0, 0, 0);\
        acc00 = __builtin_amdgcn_mfma_i32_32x32x32_i8(a01, b1, acc00, 0, 0, 0);\
        acc01 = __builtin_amdgcn_mfma_i32_32x32x32_i8(a00, b2, acc01, 0, 0, 0);\
        acc01 = __builtin_amdgcn_mfma_i32_32x32x32_i8(a01, b3, acc01, 0, 0, 0);\
        acc10 = __builtin_amdgcn_mfma_i32_32x32x32_i8(a10, b0, acc10, 0, 0, 0);\
        acc10 = __builtin_amdgcn_mfma_i32_32x32x32_i8(a11, b1, acc10, 0, 0, 0);\
        acc11 = __builtin_amdgcn_mfma_i32_32x32x32_i8(a10, b2, acc11, 0, 0, 0);\
        acc11 = __builtin_amdgcn_mfma_i32_32x32x32_i8(a11, b3, acc11, 0, 0, 0);\
        __builtin_amdgcn_s_setprio(0);                                         \
    }

// load this thread's 2 x-float4s (rows trow, trow+32) of absolute step S
#define XLD2(XA, XB, S)                                                        \
    {                                                                          \
        const int _sc = ((S) < NSTEP) ? (S) : NSTEP - 1;                       \
        XA = *reinterpret_cast<const float4*>(xr0 + (size_t)_sc * KSTEP);      \
        XB = *reinterpret_cast<const float4*>(xr0 + (size_t)32 * KDIM          \
                                                  + (size_t)_sc * KSTEP);      \
    }

// commit the pair into Af[PB], step-slot SIP (rt 0 and 1)
#define XCM2(PB, SIP, XA, XB)                                                  \
    {                                                                          \
        *reinterpret_cast<uint32_t*>(                                          \
            &Af[(PB) * 32768 + (SIP) * 4096 + awk]) = sgn4(XA);                \
        *reinterpret_cast<uint32_t*>(                                          \
            &Af[(PB) * 32768 + (SIP) * 4096 + 2048 + awk]) = sgn4(XB);         \
    }

// one oct-period: steps 8Q..8Q+7 read Af[PB]; commits A(8Q+8..+15) -> Af[PB^1]
// steady state: entering PERIOD(Q), (xA0,xA1) holds step 8Q+8 data.
#define PERIOD(Q, PB)                                                          \
    {                                                                          \
        STEP(PB, 0, Q);                                                        \
        XLD2(xB0, xB1, 8 * (Q) + 9);                                           \
        STEP(PB, 1, Q);                                                        \
        XCM2((PB) ^ 1, 0, xA0, xA1);                                           \
        XLD2(xA0, xA1, 8 * (Q) + 10);                                          \
        STEP(PB, 2, Q);                                                        \
        XCM2((PB) ^ 1, 1, xB0, xB1);                                           \
        XLD2(xB0, xB1, 8 * (Q) + 11);                                          \
        STEP(PB, 3, Q);                                                        \
        XCM2((PB) ^ 1, 2, xA0, xA1);                                           \
        XLD2(xA0, xA1, 8 * (Q) + 12);                                          \
        STEP(PB, 4, Q);                                                        \
        XCM2((PB) ^ 1, 3, xB0, xB1);                                           \
        XLD2(xB0, xB1, 8 * (Q) + 13);                                          \
        STEP(PB, 5, Q);                                                        \
        XCM2((PB) ^ 1, 4, xA0, xA1);                                           \
        XLD2(xA0, xA1, 8 * (Q) + 14);                                          \
        STEP(PB, 6, Q);                                                        \
        XCM2((PB) ^ 1, 5, xB0, xB1);                                           \
        XLD2(xB0, xB1, 8 * (Q) + 15);                                          \
        STEP(PB, 7, Q);                                                        \
        XCM2((PB) ^ 1, 6, xA0, xA1);                                           \
        XLD2(xA0, xA1, 8 * (Q) + 16);  /* = 8(Q+1)+8: next period's sip0 */    \
        XCM2((PB) ^ 1, 7, xB0, xB1);                                           \
        BARRIER();                                                             \
    }

// ------------------------------- MFMA GEMM ----------------------------------
__global__ __launch_bounds__(512, 1) void mm_kernel(const float* __restrict__ x,
                                                    const uint8_t* __restrict__ Wb2,
                                                    const float* __restrict__ bias,
                                                    float* __restrict__ C) {
    __shared__ __attribute__((aligned(16))) uint8_t Af[2 * 32768];  // 64 KB
    const int t   = threadIdx.x;
    const int l   = t & 63;
    const int wv  = t >> 6;              // wave 0..7 -> cols wv*64..+63
    const int lr  = l & 31;
    const int hi  = l >> 5;
    const int row0 = blockIdx.x * MROWS;

    // x staging (verified): thread t owns rows trow & trow+32, f4 at tak
    const int trow = t >> 4;             // 0..31
    const int tak  = (t & 15) * 4;       // 0..60
    const int awk = (tak >> 5) * 1024
                  + (trow + 32 * ((tak >> 4) & 1)) * 16 + (tak & 15);
    const float* xr0 = x + (size_t)(row0 + trow) * KDIM + tak;
    // B base (verified): n5 = wv*2 + ct; ct stride 2048, ks stride 1024
    const uint8_t* bbase = Wb2 + ((size_t)(wv * 2) * 2 * 64 + l) * 16;

    v16i acc00, acc01, acc10, acc11;
    #pragma unroll
    for (int e = 0; e < 16; ++e) { acc00[e] = 0; acc01[e] = 0;
                                   acc10[e] = 0; acc11[e] = 0; }

    float4 xA0, xA1, xB0, xB1;

    // ---- prologue: stage steps 0..7 into Af[0]; preload xA = step 8 ----
    {
        float4 xa, xb;
        XLD2(xa, xb, 0); XCM2(0, 0, xa, xb);
        XLD2(xa, xb, 1); XCM2(0, 1, xa, xb);
        XLD2(xa, xb, 2); XCM2(0, 2, xa, xb);
        XLD2(xa, xb, 3); XCM2(0, 3, xa, xb);
        XLD2(xa, xb, 4); XCM2(0, 4, xa, xb);
        XLD2(xa, xb, 5); XCM2(0, 5, xa, xb);
        XLD2(xa, xb, 6); XCM2(0, 6, xa, xb);
        XLD2(xa, xb, 7); XCM2(0, 7, xa, xb);
        XLD2(xA0, xA1, 8);
        BARRIER();
    }

    #pragma unroll 1
    for (int q = 0; q < NPER8; q += 2) {
        PERIOD(q,     0);
        PERIOD(q + 1, 1);
    }

    // ---- epilogue: C = acc + bias (verified C/D map) ----
    {
        const int col0 = wv * 64 + lr;          // ct = 0
        const int col1 = wv * 64 + 32 + lr;     // ct = 1
        const float bv0 = bias[col0], bv1 = bias[col1];
        #pragma unroll
        for (int r = 0; r < 16; ++r) {
            int crow = (r & 3) + 8 * (r >> 2) + 4 * hi;
            C[(size_t)(row0 + crow) * UNITS + col0]      = (float)acc00[r] + bv0;
            C[(size_t)(row0 + crow) * UNITS + col1]      = (float)acc01[r] + bv1;
            C[(size_t)(row0 + 32 + crow) * UNITS + col0] = (float)acc10[r] + bv0;
            C[(size_t)(row0 + 32 + crow) * UNITS + col1] = (float)acc11[r] + bv1;
        }
    }
}

extern "C" void kernel_launch(void* const* d_in, const int* in_sizes, int n_in,
                              void* d_out, int out_size, void* d_ws, size_t ws_size,
                              hipStream_t stream) {
    const float* x = (const float*)d_in[0];
    const float* W = (const float*)d_in[1];
    const float* b = (const float*)d_in[2];
    float* out = (float*)d_out;

    uint8_t* Wb2 = (uint8_t*)d_ws;   // 2 MB fragment-major packed W

    pack_w_kernel<<<(512 * 512) / 256, 256, 0, stream>>>(W, Wb2);
    mm_kernel<<<BATCH / MROWS, 512, 0, stream>>>(x, Wb2, b, out);
}